// Round 2
// baseline (458.179 us; speedup 1.0000x reference)
//
#include <hip/hip_runtime.h>

typedef _Float16 h16;
typedef __attribute__((ext_vector_type(8))) _Float16 half8;
typedef __attribute__((ext_vector_type(4))) _Float16 half4;
typedef __attribute__((ext_vector_type(4))) float f32x4;

#define LDH 264   // h-buffer row stride in fp16 elems (256 + 8 pad)
#define LDE 72    // ep-buffer row stride (64 + 8 pad)

// weight fragment offsets in d_ws (fp16 elements)
constexpr size_t OFF_P0 = 0;        // [64 ][256]
constexpr size_t OFF_P1 = 16384;    // [256][256]
constexpr size_t OFF_P2 = 81920;
constexpr size_t OFF_P3 = 147456;
constexpr size_t OFF_P4 = 212992;
constexpr size_t OFF_P5 = 278528;   // [320][256] (zero row inserted at 63)
constexpr size_t OFF_P6 = 360448;
constexpr size_t OFF_P7 = 425984;
constexpr size_t OFF_FEAT = 491520; // [256][256]
constexpr size_t OFF_VIEWS = 557056;// [288][128] (zero rows 283..287)

__device__ __forceinline__ f32x4 mfma16(half8 a, half8 b, f32x4 c) {
  return __builtin_amdgcn_mfma_f32_16x16x32_f16(a, b, c, 0, 0, 0);
}

// fp32 [K][N] row-major -> pre-swizzled fp16 MFMA B-fragments.
// Fragment (kt,nt): lane l's 8 contiguous fp16 = B[kt*32+(l>>4)*8+j][nt*16+(l&15)].
// Padded row pr maps: pr<p -> src pr ; p<=pr<p+npad -> 0 ; else src (pr-npad).
__global__ void convw_kernel(const float* __restrict__ src, h16* __restrict__ dst,
                             int Ksrc, int N, int Kp, int p, int npad) {
  int t = blockIdx.x * 256 + threadIdx.x;
  int nfrags = (Kp >> 5) * (N >> 4);
  int frag = t >> 6;
  if (frag >= nfrags) return;
  int l = t & 63;
  int ntiles = N >> 4;
  int kt = frag / ntiles;
  int nt = frag - kt * ntiles;
  int col = nt * 16 + (l & 15);
  int kbase = kt * 32 + (l >> 4) * 8;
  half8 v;
#pragma unroll
  for (int j = 0; j < 8; ++j) {
    int k = kbase + j;
    float x = 0.f;
    if (k < p) {
      x = src[(size_t)k * N + col];
    } else if (k >= p + npad) {
      int r = k - npad;
      if (r < Ksrc) x = src[(size_t)r * N + col];
    }
    v[j] = (h16)x;
  }
  *(half8*)(dst + (size_t)frag * 512 + (size_t)l * 8) = v;
}

struct Params {
  const float* pts;
  const float* views;
  const h16* wf;
  const float* pb[8];
  const float* views_b;
  const float* feat_b;
  const float* alpha_w;
  const float* alpha_b;
  const float* rgb_w;
  const float* rgb_b;
  float* out;
};

// One 64x256 GEMM step writing IN PLACE to the single h buffer.
// 4 waves, wave w owns cols [w*64, w*64+64).
// Computes (A*B)^T via swapped operands so each lane holds 4 consecutive
// output COLUMNS of one row -> packed ds_write_b64 epilogue.
// PRE_BAR: barrier between the read phase and the write phase (needed when
// dst aliases src1); a post-write barrier is always issued.
template <int KT, int KT0, bool RELU, bool PRE_BAR>
__device__ __forceinline__ void gemm256(const h16* __restrict__ src0, int ld0,
                                        const h16* __restrict__ src1, int ld1,
                                        const h16* __restrict__ wf,
                                        const float* __restrict__ bias,
                                        h16* __restrict__ dst,
                                        int w, int lrow, int lgrp, int l) {
  f32x4 acc[4][4];
  const f32x4 z = {0.f, 0.f, 0.f, 0.f};
#pragma unroll
  for (int mt = 0; mt < 4; ++mt)
#pragma unroll
    for (int nt = 0; nt < 4; ++nt) acc[mt][nt] = z;

#pragma unroll
  for (int kt = 0; kt < KT; ++kt) {
    half8 a[4];
#pragma unroll
    for (int mt = 0; mt < 4; ++mt) {
      const h16* ap;
      if (kt < KT0) ap = src0 + (size_t)(mt * 16 + lrow) * ld0 + kt * 32 + lgrp * 8;
      else          ap = src1 + (size_t)(mt * 16 + lrow) * ld1 + (kt - KT0) * 32 + lgrp * 8;
      a[mt] = *(const half8*)ap;
    }
    half8 b[4];
#pragma unroll
    for (int nt = 0; nt < 4; ++nt)
      b[nt] = *(const half8*)(wf + ((size_t)(kt * 16 + w * 4 + nt) * 64 + l) * 8);
#pragma unroll
    for (int mt = 0; mt < 4; ++mt)
#pragma unroll
      for (int nt = 0; nt < 4; ++nt)
        acc[mt][nt] = mfma16(b[nt], a[mt], acc[mt][nt]);  // (A*B)^T
  }
  if (PRE_BAR) __syncthreads();
  // D^T: lane holds out row = lrow, cols = lgrp*4 + i (within tile)
#pragma unroll
  for (int mt = 0; mt < 4; ++mt) {
    int row = mt * 16 + lrow;
#pragma unroll
    for (int nt = 0; nt < 4; ++nt) {
      int col0 = w * 64 + nt * 16 + lgrp * 4;
      f32x4 bv = *(const f32x4*)(bias + col0);
      half4 pk;
#pragma unroll
      for (int i = 0; i < 4; ++i) {
        float v = acc[mt][nt][i] + bv[i];
        if (RELU) v = fmaxf(v, 0.f);
        pk[i] = (h16)v;
      }
      *(half4*)(dst + (size_t)row * LDH + col0) = pk;
    }
  }
  __syncthreads();
}

// views GEMM: K=288 (256 from feature buf + 32 from broadcast ev), N=128.
__device__ __forceinline__ void gemm128(const h16* __restrict__ feat,
                                        const h16* __restrict__ evp,
                                        const h16* __restrict__ wf,
                                        const float* __restrict__ bias,
                                        h16* __restrict__ dst,
                                        int w, int lrow, int lgrp, int l) {
  f32x4 acc[4][2];
  const f32x4 z = {0.f, 0.f, 0.f, 0.f};
#pragma unroll
  for (int mt = 0; mt < 4; ++mt) { acc[mt][0] = z; acc[mt][1] = z; }

#pragma unroll
  for (int kt = 0; kt < 9; ++kt) {
    half8 a[4];
    if (kt < 8) {
#pragma unroll
      for (int mt = 0; mt < 4; ++mt)
        a[mt] = *(const half8*)(feat + (size_t)(mt * 16 + lrow) * LDH + kt * 32 + lgrp * 8);
    } else {
      half8 av = *(const half8*)(evp + lgrp * 8);  // same for all rows
#pragma unroll
      for (int mt = 0; mt < 4; ++mt) a[mt] = av;
    }
    half8 b[2];
#pragma unroll
    for (int nt = 0; nt < 2; ++nt)
      b[nt] = *(const half8*)(wf + ((size_t)(kt * 8 + w * 2 + nt) * 64 + l) * 8);
#pragma unroll
    for (int mt = 0; mt < 4; ++mt)
#pragma unroll
      for (int nt = 0; nt < 2; ++nt)
        acc[mt][nt] = mfma16(b[nt], a[mt], acc[mt][nt]);  // (A*B)^T
  }
  __syncthreads();  // feat buffer is also dst
#pragma unroll
  for (int mt = 0; mt < 4; ++mt) {
    int row = mt * 16 + lrow;
#pragma unroll
    for (int nt = 0; nt < 2; ++nt) {
      int col0 = w * 32 + nt * 16 + lgrp * 4;
      f32x4 bv = *(const f32x4*)(bias + col0);
      half4 pk;
#pragma unroll
      for (int i = 0; i < 4; ++i)
        pk[i] = (h16)fmaxf(acc[mt][nt][i] + bv[i], 0.f);
      *(half4*)(dst + (size_t)row * LDH + col0) = pk;
    }
  }
  __syncthreads();
}

__global__ __launch_bounds__(256, 3) void nerf_kernel(Params P) {
  __shared__ __align__(16) h16 ep[64 * LDE];
  __shared__ __align__(16) h16 h[64 * LDH];
  __shared__ __align__(16) h16 evp[32];
  __shared__ float alpha_s[64];

  const int tid = threadIdx.x;
  const int w = tid >> 6, l = tid & 63;
  const int lrow = l & 15, lgrp = l >> 4;
  const int ray = blockIdx.x;

  // ---- stage 0: embeddings (fp32 math, fp16 store) ----
  if (tid < 64) {
    const int s = tid;
    const float x0 = P.pts[((size_t)ray * 64 + s) * 3 + 0];
    const float x1 = P.pts[((size_t)ray * 64 + s) * 3 + 1];
    const float x2 = P.pts[((size_t)ray * 64 + s) * 3 + 2];
    h16* e = ep + (size_t)s * LDE;
    e[0] = (h16)x0; e[1] = (h16)x1; e[2] = (h16)x2;
#pragma unroll
    for (int f = 0; f < 10; ++f) {
      const float sc = (float)(1 << f);
      e[3 + 6 * f + 0] = (h16)sinf(x0 * sc);
      e[3 + 6 * f + 1] = (h16)sinf(x1 * sc);
      e[3 + 6 * f + 2] = (h16)sinf(x2 * sc);
      e[3 + 6 * f + 3] = (h16)cosf(x0 * sc);
      e[3 + 6 * f + 4] = (h16)cosf(x1 * sc);
      e[3 + 6 * f + 5] = (h16)cosf(x2 * sc);
    }
    e[63] = (h16)0.f;  // zero-pad col (matches zero weight row)
  } else if (tid < 96) {
    const int idx = tid - 64;  // 0..31
    float v = 0.f;
    if (idx < 27) {
      if (idx < 3) {
        v = P.views[(size_t)ray * 3 + idx];
      } else {
        const int f = (idx - 3) / 6, rem = (idx - 3) % 6, d = rem % 3;
        const float x = P.views[(size_t)ray * 3 + d] * (float)(1 << f);
        v = (rem < 3) ? sinf(x) : cosf(x);
      }
    }
    evp[idx] = (h16)v;
  }
  __syncthreads();

  // ---- pts MLP trunk (single h buffer, in-place layer updates) ----
  gemm256<2, 2, true, false>(ep, LDE, ep, LDE, P.wf + OFF_P0, P.pb[0], h, w, lrow, lgrp, l);
  gemm256<8, 0, true, true>(ep, LDE, h, LDH, P.wf + OFF_P1, P.pb[1], h, w, lrow, lgrp, l);
  gemm256<8, 0, true, true>(ep, LDE, h, LDH, P.wf + OFF_P2, P.pb[2], h, w, lrow, lgrp, l);
  gemm256<8, 0, true, true>(ep, LDE, h, LDH, P.wf + OFF_P3, P.pb[3], h, w, lrow, lgrp, l);
  gemm256<8, 0, true, true>(ep, LDE, h, LDH, P.wf + OFF_P4, P.pb[4], h, w, lrow, lgrp, l);
  // skip layer: input = [ep(63+pad), h(256)] -> K=320
  gemm256<10, 2, true, true>(ep, LDE, h, LDH, P.wf + OFF_P5, P.pb[5], h, w, lrow, lgrp, l);
  gemm256<8, 0, true, true>(ep, LDE, h, LDH, P.wf + OFF_P6, P.pb[6], h, w, lrow, lgrp, l);
  gemm256<8, 0, true, true>(ep, LDE, h, LDH, P.wf + OFF_P7, P.pb[7], h, w, lrow, lgrp, l);

  // ---- alpha = h @ alpha_w + alpha_b (no relu) ----
  {
    const int s = tid >> 2, q = tid & 3;
    float sum = 0.f;
#pragma unroll 8
    for (int k = 0; k < 64; ++k)
      sum += (float)h[(size_t)s * LDH + q * 64 + k] * P.alpha_w[q * 64 + k];
    sum += __shfl_xor(sum, 1);
    sum += __shfl_xor(sum, 2);
    if (q == 0) alpha_s[s] = sum + P.alpha_b[0];
  }

  // ---- feature = h @ feat_w + feat_b (no relu), in place ----
  gemm256<8, 0, false, true>(ep, LDE, h, LDH, P.wf + OFF_FEAT, P.feat_b, h, w, lrow, lgrp, l);

  // ---- h2 = relu([feature, ev] @ views_w + views_b) -> h[0..127] ----
  gemm128(h, evp, P.wf + OFF_VIEWS, P.views_b, h, w, lrow, lgrp, l);

  // ---- rgb + output ----
  {
    const int s = tid >> 2, q = tid & 3;
    float r0 = 0.f, r1 = 0.f, r2 = 0.f;
#pragma unroll 8
    for (int k = 0; k < 32; ++k) {
      const int kk = q * 32 + k;
      const float hv = (float)h[(size_t)s * LDH + kk];
      r0 += hv * P.rgb_w[kk * 3 + 0];
      r1 += hv * P.rgb_w[kk * 3 + 1];
      r2 += hv * P.rgb_w[kk * 3 + 2];
    }
    r0 += __shfl_xor(r0, 1); r0 += __shfl_xor(r0, 2);
    r1 += __shfl_xor(r1, 1); r1 += __shfl_xor(r1, 2);
    r2 += __shfl_xor(r2, 1); r2 += __shfl_xor(r2, 2);
    if (q == 0) {
      float4 o;
      o.x = r0 + P.rgb_b[0];
      o.y = r1 + P.rgb_b[1];
      o.z = r2 + P.rgb_b[2];
      o.w = alpha_s[s];
      *(float4*)(P.out + ((size_t)ray * 64 + s) * 4) = o;
    }
  }
}

extern "C" void kernel_launch(void* const* d_in, const int* in_sizes, int n_in,
                              void* d_out, int out_size, void* d_ws, size_t ws_size,
                              hipStream_t stream) {
  h16* wsw = (h16*)d_ws;
  auto conv = [&](int idx, int Ksrc, int N, int Kp, int p, int npad, size_t off) {
    int nfrags = (Kp / 32) * (N / 16);
    int total = nfrags * 64;
    convw_kernel<<<(total + 255) / 256, 256, 0, stream>>>(
        (const float*)d_in[idx], wsw + off, Ksrc, N, Kp, p, npad);
  };
  conv(2, 63, 256, 64, 63, 1, OFF_P0);
  conv(4, 256, 256, 256, 256, 0, OFF_P1);
  conv(6, 256, 256, 256, 256, 0, OFF_P2);
  conv(8, 256, 256, 256, 256, 0, OFF_P3);
  conv(10, 256, 256, 256, 256, 0, OFF_P4);
  conv(12, 319, 256, 320, 63, 1, OFF_P5);
  conv(14, 256, 256, 256, 256, 0, OFF_P6);
  conv(16, 256, 256, 256, 256, 0, OFF_P7);
  conv(20, 256, 256, 256, 256, 0, OFF_FEAT);
  conv(18, 283, 128, 288, 283, 5, OFF_VIEWS);

  Params P;
  P.pts = (const float*)d_in[0];
  P.views = (const float*)d_in[1];
  P.wf = wsw;
  for (int i = 0; i < 8; ++i) P.pb[i] = (const float*)d_in[3 + 2 * i];
  P.views_b = (const float*)d_in[19];
  P.feat_b = (const float*)d_in[21];
  P.alpha_w = (const float*)d_in[22];
  P.alpha_b = (const float*)d_in[23];
  P.rgb_w = (const float*)d_in[24];
  P.rgb_b = (const float*)d_in[25];
  P.out = (float*)d_out;

  nerf_kernel<<<4096, 256, 0, stream>>>(P);
}

// Round 3
// 383.102 us; speedup vs baseline: 1.1960x; 1.1960x over previous
//
#include <hip/hip_runtime.h>

typedef _Float16 h16;
typedef __attribute__((ext_vector_type(8))) _Float16 half8;
typedef __attribute__((ext_vector_type(4))) _Float16 half4;
typedef __attribute__((ext_vector_type(4))) float f32x4;

#define LDH 264   // h-buffer row stride in fp16 elems (256 + 8 pad)
#define LDE 72    // ep-buffer row stride (64 + 8 pad)

// weight fragment offsets in d_ws (fp16 elements)
constexpr size_t OFF_P0 = 0;        // [64 ][256]
constexpr size_t OFF_P1 = 16384;    // [256][256]
constexpr size_t OFF_P2 = 81920;
constexpr size_t OFF_P3 = 147456;
constexpr size_t OFF_P4 = 212992;
constexpr size_t OFF_P5 = 278528;   // [320][256] (zero row inserted at 63)
constexpr size_t OFF_P6 = 360448;
constexpr size_t OFF_P7 = 425984;
constexpr size_t OFF_FEAT = 491520; // [256][256]
constexpr size_t OFF_VIEWS = 557056;// [288][128] (zero rows 283..287)

__device__ __forceinline__ f32x4 mfma16(half8 a, half8 b, f32x4 c) {
  return __builtin_amdgcn_mfma_f32_16x16x32_f16(a, b, c, 0, 0, 0);
}

// fp32 [K][N] row-major -> pre-swizzled fp16 MFMA B-fragments.
// Fragment (kt,nt): lane l's 8 contiguous fp16 = B[kt*32+(l>>4)*8+j][nt*16+(l&15)].
// Padded row pr maps: pr<p -> src pr ; p<=pr<p+npad -> 0 ; else src (pr-npad).
__global__ void convw_kernel(const float* __restrict__ src, h16* __restrict__ dst,
                             int Ksrc, int N, int Kp, int p, int npad) {
  int t = blockIdx.x * 256 + threadIdx.x;
  int nfrags = (Kp >> 5) * (N >> 4);
  int frag = t >> 6;
  if (frag >= nfrags) return;
  int l = t & 63;
  int ntiles = N >> 4;
  int kt = frag / ntiles;
  int nt = frag - kt * ntiles;
  int col = nt * 16 + (l & 15);
  int kbase = kt * 32 + (l >> 4) * 8;
  half8 v;
#pragma unroll
  for (int j = 0; j < 8; ++j) {
    int k = kbase + j;
    float x = 0.f;
    if (k < p) {
      x = src[(size_t)k * N + col];
    } else if (k >= p + npad) {
      int r = k - npad;
      if (r < Ksrc) x = src[(size_t)r * N + col];
    }
    v[j] = (h16)x;
  }
  *(half8*)(dst + (size_t)frag * 512 + (size_t)l * 8) = v;
}

struct Params {
  const float* pts;
  const float* views;
  const h16* wf;
  const float* pb[8];
  const float* views_b;
  const float* feat_b;
  const float* alpha_w;
  const float* alpha_b;
  const float* rgb_w;
  const float* rgb_b;
  float* out;
};

// One 64x256 GEMM step writing IN PLACE to the single h buffer.
// 4 waves, wave w owns cols [w*64, w*64+64).
// Computes (A*B)^T via swapped operands so each lane holds 4 consecutive
// output COLUMNS of one row -> packed ds_write_b64 epilogue.
// PRE_BAR: barrier between the read phase and the write phase (needed when
// dst aliases src1); a post-write barrier is always issued.
template <int KT, int KT0, bool RELU, bool PRE_BAR>
__device__ __forceinline__ void gemm256(const h16* __restrict__ src0, int ld0,
                                        const h16* __restrict__ src1, int ld1,
                                        const h16* __restrict__ wf,
                                        const float* __restrict__ bias,
                                        h16* __restrict__ dst,
                                        int w, int lrow, int lgrp, int l) {
  f32x4 acc[4][4];
  const f32x4 z = {0.f, 0.f, 0.f, 0.f};
#pragma unroll
  for (int mt = 0; mt < 4; ++mt)
#pragma unroll
    for (int nt = 0; nt < 4; ++nt) acc[mt][nt] = z;

#pragma unroll
  for (int kt = 0; kt < KT; ++kt) {
    half8 a[4];
#pragma unroll
    for (int mt = 0; mt < 4; ++mt) {
      const h16* ap;
      if (kt < KT0) ap = src0 + (size_t)(mt * 16 + lrow) * ld0 + kt * 32 + lgrp * 8;
      else          ap = src1 + (size_t)(mt * 16 + lrow) * ld1 + (kt - KT0) * 32 + lgrp * 8;
      a[mt] = *(const half8*)ap;
    }
    half8 b[4];
#pragma unroll
    for (int nt = 0; nt < 4; ++nt)
      b[nt] = *(const half8*)(wf + ((size_t)(kt * 16 + w * 4 + nt) * 64 + l) * 8);
#pragma unroll
    for (int mt = 0; mt < 4; ++mt)
#pragma unroll
      for (int nt = 0; nt < 4; ++nt)
        acc[mt][nt] = mfma16(b[nt], a[mt], acc[mt][nt]);  // (A*B)^T
  }
  if (PRE_BAR) __syncthreads();
  // D^T: lane holds out row = lrow, cols = lgrp*4 + i (within tile)
#pragma unroll
  for (int mt = 0; mt < 4; ++mt) {
    int row = mt * 16 + lrow;
#pragma unroll
    for (int nt = 0; nt < 4; ++nt) {
      int col0 = w * 64 + nt * 16 + lgrp * 4;
      f32x4 bv = *(const f32x4*)(bias + col0);
      half4 pk;
#pragma unroll
      for (int i = 0; i < 4; ++i) {
        float v = acc[mt][nt][i] + bv[i];
        if (RELU) v = fmaxf(v, 0.f);
        pk[i] = (h16)v;
      }
      *(half4*)(dst + (size_t)row * LDH + col0) = pk;
    }
  }
  __syncthreads();
}

// views GEMM: K=288 (256 from feature buf + 32 from broadcast ev), N=128.
__device__ __forceinline__ void gemm128(const h16* __restrict__ feat,
                                        const h16* __restrict__ evp,
                                        const h16* __restrict__ wf,
                                        const float* __restrict__ bias,
                                        h16* __restrict__ dst,
                                        int w, int lrow, int lgrp, int l) {
  f32x4 acc[4][2];
  const f32x4 z = {0.f, 0.f, 0.f, 0.f};
#pragma unroll
  for (int mt = 0; mt < 4; ++mt) { acc[mt][0] = z; acc[mt][1] = z; }

#pragma unroll
  for (int kt = 0; kt < 9; ++kt) {
    half8 a[4];
    if (kt < 8) {
#pragma unroll
      for (int mt = 0; mt < 4; ++mt)
        a[mt] = *(const half8*)(feat + (size_t)(mt * 16 + lrow) * LDH + kt * 32 + lgrp * 8);
    } else {
      half8 av = *(const half8*)(evp + lgrp * 8);  // same for all rows
#pragma unroll
      for (int mt = 0; mt < 4; ++mt) a[mt] = av;
    }
    half8 b[2];
#pragma unroll
    for (int nt = 0; nt < 2; ++nt)
      b[nt] = *(const half8*)(wf + ((size_t)(kt * 8 + w * 2 + nt) * 64 + l) * 8);
#pragma unroll
    for (int mt = 0; mt < 4; ++mt)
#pragma unroll
      for (int nt = 0; nt < 2; ++nt)
        acc[mt][nt] = mfma16(b[nt], a[mt], acc[mt][nt]);  // (A*B)^T
  }
  __syncthreads();  // feat buffer is also dst
#pragma unroll
  for (int mt = 0; mt < 4; ++mt) {
    int row = mt * 16 + lrow;
#pragma unroll
    for (int nt = 0; nt < 2; ++nt) {
      int col0 = w * 32 + nt * 16 + lgrp * 4;
      f32x4 bv = *(const f32x4*)(bias + col0);
      half4 pk;
#pragma unroll
      for (int i = 0; i < 4; ++i)
        pk[i] = (h16)fmaxf(acc[mt][nt][i] + bv[i], 0.f);
      *(half4*)(dst + (size_t)row * LDH + col0) = pk;
    }
  }
  __syncthreads();
}

__global__ __launch_bounds__(256, 2) void nerf_kernel(Params P) {
  __shared__ __align__(16) h16 ep[64 * LDE];
  __shared__ __align__(16) h16 h[64 * LDH];
  __shared__ __align__(16) h16 evp[32];
  __shared__ float alpha_s[64];

  const int tid = threadIdx.x;
  const int w = tid >> 6, l = tid & 63;
  const int lrow = l & 15, lgrp = l >> 4;
  const int ray = blockIdx.x;

  // ---- stage 0: embeddings (fp32 math, fp16 store) ----
  if (tid < 64) {
    const int s = tid;
    const float x0 = P.pts[((size_t)ray * 64 + s) * 3 + 0];
    const float x1 = P.pts[((size_t)ray * 64 + s) * 3 + 1];
    const float x2 = P.pts[((size_t)ray * 64 + s) * 3 + 2];
    h16* e = ep + (size_t)s * LDE;
    e[0] = (h16)x0; e[1] = (h16)x1; e[2] = (h16)x2;
#pragma unroll
    for (int f = 0; f < 10; ++f) {
      const float sc = (float)(1 << f);
      e[3 + 6 * f + 0] = (h16)sinf(x0 * sc);
      e[3 + 6 * f + 1] = (h16)sinf(x1 * sc);
      e[3 + 6 * f + 2] = (h16)sinf(x2 * sc);
      e[3 + 6 * f + 3] = (h16)cosf(x0 * sc);
      e[3 + 6 * f + 4] = (h16)cosf(x1 * sc);
      e[3 + 6 * f + 5] = (h16)cosf(x2 * sc);
    }
    e[63] = (h16)0.f;  // zero-pad col (matches zero weight row)
  } else if (tid < 96) {
    const int idx = tid - 64;  // 0..31
    float v = 0.f;
    if (idx < 27) {
      if (idx < 3) {
        v = P.views[(size_t)ray * 3 + idx];
      } else {
        const int f = (idx - 3) / 6, rem = (idx - 3) % 6, d = rem % 3;
        const float x = P.views[(size_t)ray * 3 + d] * (float)(1 << f);
        v = (rem < 3) ? sinf(x) : cosf(x);
      }
    }
    evp[idx] = (h16)v;
  }
  __syncthreads();

  // ---- pts MLP trunk (single h buffer, in-place layer updates) ----
  gemm256<2, 2, true, false>(ep, LDE, ep, LDE, P.wf + OFF_P0, P.pb[0], h, w, lrow, lgrp, l);
  gemm256<8, 0, true, true>(ep, LDE, h, LDH, P.wf + OFF_P1, P.pb[1], h, w, lrow, lgrp, l);
  gemm256<8, 0, true, true>(ep, LDE, h, LDH, P.wf + OFF_P2, P.pb[2], h, w, lrow, lgrp, l);
  gemm256<8, 0, true, true>(ep, LDE, h, LDH, P.wf + OFF_P3, P.pb[3], h, w, lrow, lgrp, l);
  gemm256<8, 0, true, true>(ep, LDE, h, LDH, P.wf + OFF_P4, P.pb[4], h, w, lrow, lgrp, l);
  // skip layer: input = [ep(63+pad), h(256)] -> K=320
  gemm256<10, 2, true, true>(ep, LDE, h, LDH, P.wf + OFF_P5, P.pb[5], h, w, lrow, lgrp, l);
  gemm256<8, 0, true, true>(ep, LDE, h, LDH, P.wf + OFF_P6, P.pb[6], h, w, lrow, lgrp, l);
  gemm256<8, 0, true, true>(ep, LDE, h, LDH, P.wf + OFF_P7, P.pb[7], h, w, lrow, lgrp, l);

  // ---- alpha = h @ alpha_w + alpha_b (no relu) ----
  {
    const int s = tid >> 2, q = tid & 3;
    float sum = 0.f;
#pragma unroll 8
    for (int k = 0; k < 64; ++k)
      sum += (float)h[(size_t)s * LDH + q * 64 + k] * P.alpha_w[q * 64 + k];
    sum += __shfl_xor(sum, 1);
    sum += __shfl_xor(sum, 2);
    if (q == 0) alpha_s[s] = sum + P.alpha_b[0];
  }

  // ---- feature = h @ feat_w + feat_b (no relu), in place ----
  gemm256<8, 0, false, true>(ep, LDE, h, LDH, P.wf + OFF_FEAT, P.feat_b, h, w, lrow, lgrp, l);

  // ---- h2 = relu([feature, ev] @ views_w + views_b) -> h[0..127] ----
  gemm128(h, evp, P.wf + OFF_VIEWS, P.views_b, h, w, lrow, lgrp, l);

  // ---- rgb + output ----
  {
    const int s = tid >> 2, q = tid & 3;
    float r0 = 0.f, r1 = 0.f, r2 = 0.f;
#pragma unroll 8
    for (int k = 0; k < 32; ++k) {
      const int kk = q * 32 + k;
      const float hv = (float)h[(size_t)s * LDH + kk];
      r0 += hv * P.rgb_w[kk * 3 + 0];
      r1 += hv * P.rgb_w[kk * 3 + 1];
      r2 += hv * P.rgb_w[kk * 3 + 2];
    }
    r0 += __shfl_xor(r0, 1); r0 += __shfl_xor(r0, 2);
    r1 += __shfl_xor(r1, 1); r1 += __shfl_xor(r1, 2);
    r2 += __shfl_xor(r2, 1); r2 += __shfl_xor(r2, 2);
    if (q == 0) {
      float4 o;
      o.x = r0 + P.rgb_b[0];
      o.y = r1 + P.rgb_b[1];
      o.z = r2 + P.rgb_b[2];
      o.w = alpha_s[s];
      *(float4*)(P.out + ((size_t)ray * 64 + s) * 4) = o;
    }
  }
}

extern "C" void kernel_launch(void* const* d_in, const int* in_sizes, int n_in,
                              void* d_out, int out_size, void* d_ws, size_t ws_size,
                              hipStream_t stream) {
  h16* wsw = (h16*)d_ws;
  auto conv = [&](int idx, int Ksrc, int N, int Kp, int p, int npad, size_t off) {
    int nfrags = (Kp / 32) * (N / 16);
    int total = nfrags * 64;
    convw_kernel<<<(total + 255) / 256, 256, 0, stream>>>(
        (const float*)d_in[idx], wsw + off, Ksrc, N, Kp, p, npad);
  };
  conv(2, 63, 256, 64, 63, 1, OFF_P0);
  conv(4, 256, 256, 256, 256, 0, OFF_P1);
  conv(6, 256, 256, 256, 256, 0, OFF_P2);
  conv(8, 256, 256, 256, 256, 0, OFF_P3);
  conv(10, 256, 256, 256, 256, 0, OFF_P4);
  conv(12, 319, 256, 320, 63, 1, OFF_P5);
  conv(14, 256, 256, 256, 256, 0, OFF_P6);
  conv(16, 256, 256, 256, 256, 0, OFF_P7);
  conv(20, 256, 256, 256, 256, 0, OFF_FEAT);
  conv(18, 283, 128, 288, 283, 5, OFF_VIEWS);

  Params P;
  P.pts = (const float*)d_in[0];
  P.views = (const float*)d_in[1];
  P.wf = wsw;
  for (int i = 0; i < 8; ++i) P.pb[i] = (const float*)d_in[3 + 2 * i];
  P.views_b = (const float*)d_in[19];
  P.feat_b = (const float*)d_in[21];
  P.alpha_w = (const float*)d_in[22];
  P.alpha_b = (const float*)d_in[23];
  P.rgb_w = (const float*)d_in[24];
  P.rgb_b = (const float*)d_in[25];
  P.out = (float*)d_out;

  nerf_kernel<<<4096, 256, 0, stream>>>(P);
}